// Round 16
// baseline (194.282 us; speedup 1.0000x reference)
//
#include <hip/hip_runtime.h>

#define N_NODES 50000
#define N_EDGES 500000
#define DIM 128
#define KC 1024
#define CAP 64
#define EPSV 1e-8f
#define LO_SCALE 4096.0f
#define INV_LO_SCALE (1.0f / 4096.0f)
#define NSPLIT 2

typedef _Float16 f16x8 __attribute__((ext_vector_type(8)));
typedef _Float16 f16x4 __attribute__((ext_vector_type(4)));
typedef _Float16 f16x2 __attribute__((ext_vector_type(2)));
typedef float f32x4 __attribute__((ext_vector_type(4)));

// map float to order-preserving uint (for packed u64 argmax keys)
__device__ __forceinline__ unsigned ford(float f) {
    unsigned b = __float_as_uint(f);
    return (b & 0x80000000u) ? ~b : (b | 0x80000000u);
}

// ---------------- Stage 1a: bucket edges by dst (int atomics only) ----------------
__global__ void fill_buckets_k(const int* __restrict__ ei, int* __restrict__ bucket,
                               int* __restrict__ cursor) {
    int e = blockIdx.x * blockDim.x + threadIdx.x;
    if (e >= N_EDGES) return;
    int src = ei[e];
    int dst = ei[N_EDGES + e];
    int pos = atomicAdd(cursor + dst, 1);
    if (pos < CAP) bucket[dst * CAP + pos] = src;
}

// ---------------- Stage 1b+2: deterministic mean-aggregate + normalize + fp16 split
// v2: 2 nodes per wave (32-lane halves). One 15-step bitonic sorts both halves;
// gather is float4/lane (512B rows). Slow path (64-lane, original) for deg>32.
__global__ void agg_norm_k(const float* __restrict__ x, const int* __restrict__ bucket,
                           const int* __restrict__ cursor, float* __restrict__ h,
                           _Float16* __restrict__ Ahi, _Float16* __restrict__ Alo) {
    const int lane = threadIdx.x & 63;
    const int wv = threadIdx.x >> 6;
    const int half = lane >> 5, q = lane & 31;
    const int n = blockIdx.x * 8 + wv * 2 + half;   // 6250 blocks * 4 waves * 2 nodes

    int cnt_mine = cursor[n];
    if (cnt_mine > CAP) cnt_mine = CAP;
    int cnt_other = __shfl_xor(cnt_mine, 32);
    int cmax = max(cnt_mine, cnt_other);

    if (cmax <= 32) {
        // ---------- fast path: both nodes deg<=32 (P(miss) ~ 1e-8) ----------
        int v = (q < cnt_mine) ? bucket[n * CAP + q] : 0x7fffffff;
#pragma unroll
        for (int k = 2; k <= 32; k <<= 1) {
#pragma unroll
            for (int j = k >> 1; j >= 1; j >>= 1) {
                int other = __shfl_xor(v, j);
                bool lower = ((q & j) == 0);
                bool asc = ((q & k) == 0);
                int mn = min(v, other), mx = max(v, other);
                v = (lower == asc) ? mn : mx;
            }
        }
        const float4* x4p = (const float4*)x;
        float4 a4 = make_float4(0.f, 0.f, 0.f, 0.f);
        const int base = half << 5;
        for (int j = 0; j < cmax; j += 2) {
            int s0 = __shfl(v, base + j);
            int s1 = __shfl(v, base + j + 1);
            if (j < cnt_mine) {
                float4 t = x4p[(size_t)s0 * 32 + q];
                a4.x += t.x; a4.y += t.y; a4.z += t.z; a4.w += t.w;
            }
            if (j + 1 < cnt_mine) {
                float4 t = x4p[(size_t)s1 * 32 + q];
                a4.x += t.x; a4.y += t.y; a4.z += t.z; a4.w += t.w;
            }
        }
        float inv = 1.0f / (float)(cnt_mine > 0 ? cnt_mine : 1);
        float4 h4;
        h4.x = a4.x * inv; h4.y = a4.y * inv; h4.z = a4.z * inv; h4.w = a4.w * inv;
        float ss = h4.x * h4.x + h4.y * h4.y + h4.z * h4.z + h4.w * h4.w;
#pragma unroll
        for (int o = 1; o < 32; o <<= 1) ss += __shfl_xor(ss, o);
        float sc = 1.0f / (sqrtf(ss) + EPSV);
        float4 hn4;
        hn4.x = h4.x * sc; hn4.y = h4.y * sc; hn4.z = h4.z * sc; hn4.w = h4.w * sc;

        ((float4*)h)[(size_t)n * 32 + q] = h4;
        _Float16 h0 = (_Float16)hn4.x, h1 = (_Float16)hn4.y;
        _Float16 h2 = (_Float16)hn4.z, h3 = (_Float16)hn4.w;
        f16x4 ph = {h0, h1, h2, h3};
        f16x4 pl = {(_Float16)((hn4.x - (float)h0) * LO_SCALE),
                    (_Float16)((hn4.y - (float)h1) * LO_SCALE),
                    (_Float16)((hn4.z - (float)h2) * LO_SCALE),
                    (_Float16)((hn4.w - (float)h3) * LO_SCALE)};
        *(f16x4*)(Ahi + (size_t)n * DIM + q * 4) = ph;
        *(f16x4*)(Alo + (size_t)n * DIM + q * 4) = pl;
    } else {
        // ---------- slow path: original 64-lane algorithm, run for both nodes ----
        for (int tt = 0; tt < 2; ++tt) {
            int nn = blockIdx.x * 8 + wv * 2 + tt;
            int cnt = cursor[nn];
            if (cnt > CAP) cnt = CAP;
            int v = (lane < cnt) ? bucket[nn * CAP + lane] : 0x7fffffff;
#pragma unroll
            for (int k = 2; k <= 64; k <<= 1) {
#pragma unroll
                for (int j = k >> 1; j >= 1; j >>= 1) {
                    int other = __shfl_xor(v, j);
                    bool lower = ((lane & j) == 0);
                    bool asc = ((lane & k) == 0);
                    int mn = min(v, other), mx = max(v, other);
                    v = (lower == asc) ? mn : mx;
                }
            }
            const float2* x2 = (const float2*)x;
            float ax = 0.f, ay = 0.f;
            for (int j = 0; j < cnt; ++j) {
                int s = __shfl(v, j);
                float2 t = x2[(size_t)s * 64 + lane];
                ax += t.x; ay += t.y;
            }
            float degf = (float)(cnt > 0 ? cnt : 1);
            float hx = ax / degf, hy = ay / degf;
            float ss = hx * hx + hy * hy;
#pragma unroll
            for (int o = 1; o < 64; o <<= 1) ss += __shfl_xor(ss, o);
            float denom = sqrtf(ss) + EPSV;
            float hnx = hx / denom, hny = hy / denom;
            ((float2*)h)[(size_t)nn * 64 + lane] = make_float2(hx, hy);
            _Float16 hix = (_Float16)hnx, hiy = (_Float16)hny;
            f16x2 ph; ph[0] = hix; ph[1] = hiy;
            f16x2 pl; pl[0] = (_Float16)((hnx - (float)hix) * LO_SCALE);
            pl[1] = (_Float16)((hny - (float)hiy) * LO_SCALE);
            *(f16x2*)(Ahi + (size_t)nn * DIM + lane * 2) = ph;
            *(f16x2*)(Alo + (size_t)nn * DIM + lane * 2) = pl;
        }
    }
}

// ---------------- Stage 3: LDS-shared MFMA fp16x3 sim, 2-wave blocks --------------
// R16: 128-thread blocks (2 waves x 32 rows) -> grid (782,2) = 1564 blocks,
// 6.1-deep grid with 5 resident blocks/CU (LDS-capped) instead of 3.05-deep
// 4-wave blocks (R15: occupancy 20%, 2.3x above LDS floor from ramp/straggler).
// Same per-row LDS/FLOP ratios; reg-staging (R14 lesson); private partial
// stores (R12/R13 lessons: y<=2, no cross-XCD atomics).
#define SWZ14(u) ((u) ^ ((((u) >> 8) & 7) << 4))

__global__ __launch_bounds__(128, 2) void sim_mfma9_k(const _Float16* __restrict__ Ahi,
                                                      const _Float16* __restrict__ Alo,
                                                      unsigned long long* __restrict__ part) {
    __shared__ __align__(16) char Bs[2][16384];  // [dbuf][hi 8192 | lo 8192]
    const int lane = threadIdx.x & 63;
    const int wv = threadIdx.x >> 6;             // 0..1
    const int r16 = lane & 15, kg = lane >> 4;
    const int m0 = blockIdx.x * 64 + wv * 32;
    const int cbase = blockIdx.y * 65536;        // element base of this half's B panel
    const int col0 = blockIdx.y * 512;

    // ---- A rows -> regs (2 Mtiles x 4 ksub x 2 planes = 64 VGPR), read once ----
    int ar0 = m0 + r16;      if (ar0 > N_NODES - 1) ar0 = N_NODES - 1;
    int ar1 = m0 + 16 + r16; if (ar1 > N_NODES - 1) ar1 = N_NODES - 1;
    f16x8 ah0[4], al0[4], ah1[4], al1[4];
#pragma unroll
    for (int ks = 0; ks < 4; ++ks) {
        size_t o0 = (size_t)ar0 * DIM + ks * 32 + kg * 8;
        size_t o1 = (size_t)ar1 * DIM + ks * 32 + kg * 8;
        ah0[ks] = *(const f16x8*)(Ahi + o0);
        al0[ks] = *(const f16x8*)(Alo + o0);
        ah1[ks] = *(const f16x8*)(Ahi + o1);
        al1[ks] = *(const f16x8*)(Alo + o1);
    }

    // ---- staging: per wave 8KB of the 16KB chunk (4 slots x 1KB per plane) ----
    const int u0 = wv * 4096 + lane * 16;   // linear byte slots in 8KB plane
    const int u1 = u0 + 1024;
    const int u2 = u0 + 2048;
    const int u3 = u0 + 3072;
    const int d0 = SWZ14(u0), d1 = SWZ14(u1), d2 = SWZ14(u2), d3 = SWZ14(u3);
    const int e0 = u0 >> 1, e1 = u1 >> 1, e2 = u2 >> 1, e3 = u3 >> 1;

    float best0_0 = -1e30f, best0_1 = -1e30f, best0_2 = -1e30f, best0_3 = -1e30f;
    float best1_0 = -1e30f, best1_1 = -1e30f, best1_2 = -1e30f, best1_3 = -1e30f;
    int bi0_0 = 0, bi0_1 = 0, bi0_2 = 0, bi0_3 = 0;
    int bi1_0 = 0, bi1_1 = 0, bi1_2 = 0, bi1_3 = 0;

    const int rbase = r16 * 256;
    const int x4 = (r16 & 7) << 4;

    // prologue: stage chunk 0
    f16x8 sH0 = *(const f16x8*)(Ahi + cbase + e0);
    f16x8 sH1 = *(const f16x8*)(Ahi + cbase + e1);
    f16x8 sH2 = *(const f16x8*)(Ahi + cbase + e2);
    f16x8 sH3 = *(const f16x8*)(Ahi + cbase + e3);
    f16x8 sL0 = *(const f16x8*)(Alo + cbase + e0);
    f16x8 sL1 = *(const f16x8*)(Alo + cbase + e1);
    f16x8 sL2 = *(const f16x8*)(Alo + cbase + e2);
    f16x8 sL3 = *(const f16x8*)(Alo + cbase + e3);
    {
        char* bc = &Bs[0][0];
        *(f16x8*)(bc + d0) = sH0; *(f16x8*)(bc + d1) = sH1;
        *(f16x8*)(bc + d2) = sH2; *(f16x8*)(bc + d3) = sH3;
        *(f16x8*)(bc + 8192 + d0) = sL0; *(f16x8*)(bc + 8192 + d1) = sL1;
        *(f16x8*)(bc + 8192 + d2) = sL2; *(f16x8*)(bc + 8192 + d3) = sL3;
    }
    __syncthreads();

    for (int kc = 0; kc < 16; ++kc) {
        const int cur = kc & 1;
        if (kc < 15) {  // issue next chunk's global loads (fly under compute)
            int go = cbase + (kc + 1) * 4096;
            sH0 = *(const f16x8*)(Ahi + go + e0);
            sH1 = *(const f16x8*)(Ahi + go + e1);
            sH2 = *(const f16x8*)(Ahi + go + e2);
            sH3 = *(const f16x8*)(Ahi + go + e3);
            sL0 = *(const f16x8*)(Alo + go + e0);
            sL1 = *(const f16x8*)(Alo + go + e1);
            sL2 = *(const f16x8*)(Alo + go + e2);
            sL3 = *(const f16x8*)(Alo + go + e3);
        }
        char* bc = &Bs[cur][0];
#pragma unroll
        for (int ns = 0; ns < 2; ++ns) {
            f32x4 c1a = (f32x4){0.f, 0.f, 0.f, 0.f};
            f32x4 c2a = (f32x4){0.f, 0.f, 0.f, 0.f};
            f32x4 c1b = (f32x4){0.f, 0.f, 0.f, 0.f};
            f32x4 c2b = (f32x4){0.f, 0.f, 0.f, 0.f};
#pragma unroll
            for (int ks = 0; ks < 4; ++ks) {
                int off = ns * 4096 + rbase + ((ks * 64 + kg * 16) ^ x4);
                f16x8 bh = *(const f16x8*)(bc + off);
                f16x8 bl = *(const f16x8*)(bc + 8192 + off);
                c1a = __builtin_amdgcn_mfma_f32_16x16x32_f16(ah0[ks], bh, c1a, 0, 0, 0);
                c2a = __builtin_amdgcn_mfma_f32_16x16x32_f16(ah0[ks], bl, c2a, 0, 0, 0);
                c2a = __builtin_amdgcn_mfma_f32_16x16x32_f16(al0[ks], bh, c2a, 0, 0, 0);
                c1b = __builtin_amdgcn_mfma_f32_16x16x32_f16(ah1[ks], bh, c1b, 0, 0, 0);
                c2b = __builtin_amdgcn_mfma_f32_16x16x32_f16(ah1[ks], bl, c2b, 0, 0, 0);
                c2b = __builtin_amdgcn_mfma_f32_16x16x32_f16(al1[ks], bh, c2b, 0, 0, 0);
            }
            int col = col0 + kc * 32 + ns * 16 + r16;   // ascending per lane
            float s;
            s = c1a[0] + c2a[0] * INV_LO_SCALE; if (s > best0_0) { best0_0 = s; bi0_0 = col; }
            s = c1a[1] + c2a[1] * INV_LO_SCALE; if (s > best0_1) { best0_1 = s; bi0_1 = col; }
            s = c1a[2] + c2a[2] * INV_LO_SCALE; if (s > best0_2) { best0_2 = s; bi0_2 = col; }
            s = c1a[3] + c2a[3] * INV_LO_SCALE; if (s > best0_3) { best0_3 = s; bi0_3 = col; }
            s = c1b[0] + c2b[0] * INV_LO_SCALE; if (s > best1_0) { best1_0 = s; bi1_0 = col; }
            s = c1b[1] + c2b[1] * INV_LO_SCALE; if (s > best1_1) { best1_1 = s; bi1_1 = col; }
            s = c1b[2] + c2b[2] * INV_LO_SCALE; if (s > best1_2) { best1_2 = s; bi1_2 = col; }
            s = c1b[3] + c2b[3] * INV_LO_SCALE; if (s > best1_3) { best1_3 = s; bi1_3 = col; }
        }
        if (kc < 15) {  // write next chunk into the other buffer
            char* bn = &Bs[cur ^ 1][0];
            *(f16x8*)(bn + d0) = sH0; *(f16x8*)(bn + d1) = sH1;
            *(f16x8*)(bn + d2) = sH2; *(f16x8*)(bn + d3) = sH3;
            *(f16x8*)(bn + 8192 + d0) = sL0; *(f16x8*)(bn + 8192 + d1) = sL1;
            *(f16x8*)(bn + 8192 + d2) = sL2; *(f16x8*)(bn + 8192 + d3) = sL3;
        }
        __syncthreads();
    }

    // ---- finalize: 16-lane reduce, then PRIVATE partial store (no atomics) ----
    float bestA[8] = {best0_0, best0_1, best0_2, best0_3,
                      best1_0, best1_1, best1_2, best1_3};
    int bidxA[8] = {bi0_0, bi0_1, bi0_2, bi0_3, bi1_0, bi1_1, bi1_2, bi1_3};
    unsigned long long* prow = part + (size_t)blockIdx.y * N_NODES;
#pragma unroll
    for (int qq = 0; qq < 8; ++qq) {
        float b = bestA[qq];
        int bi = bidxA[qq];
#pragma unroll
        for (int o = 1; o < 16; o <<= 1) {
            float os = __shfl_xor(b, o);
            int oi = __shfl_xor(bi, o);
            if (os > b || (os == b && oi < bi)) { b = os; bi = oi; }
        }
        if (r16 == 0) {
            int gr = m0 + (qq >> 2) * 16 + kg * 4 + (qq & 3);  // C/D row = kg*4 + reg
            if (gr < N_NODES) {
                prow[gr] = ((unsigned long long)ford(b) << 32) | (unsigned)(KC - 1 - bi);
            }
        }
    }
}

// ---------------- Stage 3b: reduce partials -> assign, + cluster counts ----------
__global__ void decode_count_k(const unsigned long long* __restrict__ part,
                               int* __restrict__ assign, int* __restrict__ counts) {
    int n = blockIdx.x * 256 + threadIdx.x;
    if (n >= N_NODES) return;
    unsigned long long k0 = part[n];
    unsigned long long k1 = part[(size_t)N_NODES + n];
    unsigned long long m = k0 > k1 ? k0 : k1;
    int a = (KC - 1) - (int)(unsigned)(m & 0xFFFFFFFFull);
    assign[n] = a;
    atomicAdd(counts + a, 1);
}

// ---------------- Stage 4: scan (shfl-based, 3 barriers) + compact ----------------
__global__ void scan_k(const int* __restrict__ counts, int* __restrict__ offs,
                       int* __restrict__ ccur) {
    __shared__ int wsum[4];
    int t = threadIdx.x;              // 256 threads x 4 elements
    int lane = t & 63, wv = t >> 6;
    int4 v = ((const int4*)counts)[t];
    int s = v.x + v.y + v.z + v.w;
    int ps = s;
#pragma unroll
    for (int o = 1; o < 64; o <<= 1) {
        int u = __shfl_up(ps, o);
        if (lane >= o) ps += u;
    }
    if (lane == 63) wsum[wv] = ps;
    __syncthreads();
    int base = 0;
#pragma unroll
    for (int w = 0; w < 4; ++w) base += (w < wv) ? wsum[w] : 0;
    int excl = base + ps - s;
    int4 o4;
    o4.x = excl;
    o4.y = excl + v.x;
    o4.z = excl + v.x + v.y;
    o4.w = excl + v.x + v.y + v.z;
    ((int4*)offs)[t] = o4;
    ((int4*)ccur)[t] = o4;
}

__global__ void fill_clist_k(const int* __restrict__ assign, int* __restrict__ ccur,
                             int* __restrict__ clist) {
    int n = blockIdx.x * 256 + threadIdx.x;
    if (n >= N_NODES) return;
    int p = atomicAdd(ccur + assign[n], 1);
    clist[p] = n;
}

// ---------------- Stage 5 (fused): xc sum + y-row + direct scatter to out --------
__global__ void xcy_out_k(const float* __restrict__ h, const int* __restrict__ clist,
                          const int* __restrict__ offs, const int* __restrict__ counts,
                          const float* __restrict__ W1, const float* __restrict__ b1,
                          float* __restrict__ out) {
    __shared__ float xr[DIM];
    int c = blockIdx.x, t = threadIdx.x;  // 1024 blocks x 128 threads
    int s = offs[c], cnt = counts[c];
    float acc = 0.f;
    for (int i = 0; i < cnt; ++i) {
        int n = clist[s + i];
        acc += h[(size_t)n * DIM + t];
    }
    xr[t] = acc / (float)(cnt > 0 ? cnt : 1);
    __syncthreads();

    const float4* w4 = (const float4*)(W1 + t * DIM);
    float a0 = 0.f, a1 = 0.f, a2 = 0.f, a3 = 0.f;
#pragma unroll
    for (int kk = 0; kk < 32; ++kk) {
        float4 w = w4[kk];
        a0 = fmaf(xr[4 * kk + 0], w.x, a0);
        a1 = fmaf(xr[4 * kk + 1], w.y, a1);
        a2 = fmaf(xr[4 * kk + 2], w.z, a2);
        a3 = fmaf(xr[4 * kk + 3], w.w, a3);
    }
    float yv = (a0 + a1) + (a2 + a3) + b1[t];

    for (int i = 0; i < cnt; ++i) {
        int n = clist[s + i];
        out[(size_t)n * DIM + t] = yv;   // coalesced 512B row write per member
    }
}

extern "C" void kernel_launch(void* const* d_in, const int* in_sizes, int n_in,
                              void* d_out, int out_size, void* d_ws, size_t ws_size,
                              hipStream_t stream) {
    const float* x  = (const float*)d_in[0];
    const int*   ei = (const int*)d_in[1];
    const float* W1 = (const float*)d_in[2];
    const float* b1 = (const float*)d_in[3];
    float* out = (float*)d_out;

    char* ws = (char*)d_ws;
    // ws layout (bytes):
    //   h      @ 0          : 50000*128*4 = 25,600,000
    //   bucket @ 25,600,000 : 50000*64*4  = 12,800,000  (dead after agg_norm:
    //       clist @ 25,600,000 : 200,000 | offs @ 25,800,000 : 4,096
    //       ccur  @ 25,804,096 : 4,096   | part @ 25,808,192 : 800,000 )
    //   cursor @ 38,400,000 : 50000*4     =    200,000
    //   counts @ 38,600,000 : 1024*4      =      4,096
    //   assign @ 39,128,384 : 50000*4     =    200,000
    float* h      = (float*)(ws);
    int*   bucket = (int*)(ws + 25600000);
    int*   clist  = (int*)(ws + 25600000);
    int*   offs   = (int*)(ws + 25800000);
    int*   ccur   = (int*)(ws + 25804096);
    unsigned long long* part = (unsigned long long*)(ws + 25808192);
    int*   cursor = (int*)(ws + 38400000);
    int*   counts = (int*)(ws + 38600000);
    int*   assign = (int*)(ws + 39128384);

    // d_out (25.6 MB) temporarily holds the split fp16 planes of hn:
    //   Ahi @ 0 (12.8 MB), Alo @ 12.8 MB. Dead after sim; fully overwritten
    //   by xcy_out_k (every node belongs to exactly one cluster).
    _Float16* Ahi = (_Float16*)d_out;
    _Float16* Alo = (_Float16*)((char*)d_out + 12800000);

    hipMemsetAsync(ws + 38400000, 0, 204096, stream);  // cursor + counts

    fill_buckets_k<<<(N_EDGES + 255) / 256, 256, 0, stream>>>(ei, bucket, cursor);
    agg_norm_k<<<N_NODES / 8, 256, 0, stream>>>(x, bucket, cursor, h, Ahi, Alo);
    sim_mfma9_k<<<dim3((N_NODES + 63) / 64, NSPLIT), 128, 0, stream>>>(Ahi, Alo, part);
    decode_count_k<<<(N_NODES + 255) / 256, 256, 0, stream>>>(part, assign, counts);
    scan_k<<<1, 256, 0, stream>>>(counts, offs, ccur);
    fill_clist_k<<<(N_NODES + 255) / 256, 256, 0, stream>>>(assign, ccur, clist);
    xcy_out_k<<<KC, 128, 0, stream>>>(h, clist, offs, counts, W1, b1, out);
}

// Round 17
// 174.843 us; speedup vs baseline: 1.1112x; 1.1112x over previous
//
#include <hip/hip_runtime.h>

#define N_NODES 50000
#define N_EDGES 500000
#define DIM 128
#define KC 1024
#define CAP 64
#define EPSV 1e-8f
#define LO_SCALE 4096.0f
#define INV_LO_SCALE (1.0f / 4096.0f)

typedef _Float16 f16x8 __attribute__((ext_vector_type(8)));
typedef _Float16 f16x4 __attribute__((ext_vector_type(4)));
typedef _Float16 f16x2 __attribute__((ext_vector_type(2)));
typedef float f32x4 __attribute__((ext_vector_type(4)));

// ---------------- Stage 1a: bucket edges by dst (int atomics only) ----------------
__global__ void fill_buckets_k(const int* __restrict__ ei, int* __restrict__ bucket,
                               int* __restrict__ cursor) {
    int e = blockIdx.x * blockDim.x + threadIdx.x;
    if (e >= N_EDGES) return;
    int src = ei[e];
    int dst = ei[N_EDGES + e];
    int pos = atomicAdd(cursor + dst, 1);
    if (pos < CAP) bucket[dst * CAP + pos] = src;
}

// ---------------- Stage 1b+2: deterministic mean-aggregate + normalize + fp16 split
// v2: 2 nodes per wave (32-lane halves). One 15-step bitonic sorts both halves;
// gather is float4/lane (512B rows). Slow path (64-lane, original) for deg>32.
__global__ void agg_norm_k(const float* __restrict__ x, const int* __restrict__ bucket,
                           const int* __restrict__ cursor, float* __restrict__ h,
                           _Float16* __restrict__ Ahi, _Float16* __restrict__ Alo) {
    const int lane = threadIdx.x & 63;
    const int wv = threadIdx.x >> 6;
    const int half = lane >> 5, q = lane & 31;
    const int n = blockIdx.x * 8 + wv * 2 + half;   // 6250 blocks * 4 waves * 2 nodes

    int cnt_mine = cursor[n];
    if (cnt_mine > CAP) cnt_mine = CAP;
    int cnt_other = __shfl_xor(cnt_mine, 32);
    int cmax = max(cnt_mine, cnt_other);

    if (cmax <= 32) {
        // ---------- fast path: both nodes deg<=32 (P(miss) ~ 1e-8) ----------
        int v = (q < cnt_mine) ? bucket[n * CAP + q] : 0x7fffffff;
#pragma unroll
        for (int k = 2; k <= 32; k <<= 1) {
#pragma unroll
            for (int j = k >> 1; j >= 1; j >>= 1) {
                int other = __shfl_xor(v, j);
                bool lower = ((q & j) == 0);
                bool asc = ((q & k) == 0);
                int mn = min(v, other), mx = max(v, other);
                v = (lower == asc) ? mn : mx;
            }
        }
        const float4* x4p = (const float4*)x;
        float4 a4 = make_float4(0.f, 0.f, 0.f, 0.f);
        const int base = half << 5;
        for (int j = 0; j < cmax; j += 2) {
            int s0 = __shfl(v, base + j);
            int s1 = __shfl(v, base + j + 1);
            if (j < cnt_mine) {
                float4 t = x4p[(size_t)s0 * 32 + q];
                a4.x += t.x; a4.y += t.y; a4.z += t.z; a4.w += t.w;
            }
            if (j + 1 < cnt_mine) {
                float4 t = x4p[(size_t)s1 * 32 + q];
                a4.x += t.x; a4.y += t.y; a4.z += t.z; a4.w += t.w;
            }
        }
        float inv = 1.0f / (float)(cnt_mine > 0 ? cnt_mine : 1);
        float4 h4;
        h4.x = a4.x * inv; h4.y = a4.y * inv; h4.z = a4.z * inv; h4.w = a4.w * inv;
        float ss = h4.x * h4.x + h4.y * h4.y + h4.z * h4.z + h4.w * h4.w;
#pragma unroll
        for (int o = 1; o < 32; o <<= 1) ss += __shfl_xor(ss, o);
        float sc = 1.0f / (sqrtf(ss) + EPSV);
        float4 hn4;
        hn4.x = h4.x * sc; hn4.y = h4.y * sc; hn4.z = h4.z * sc; hn4.w = h4.w * sc;

        ((float4*)h)[(size_t)n * 32 + q] = h4;
        _Float16 h0 = (_Float16)hn4.x, h1 = (_Float16)hn4.y;
        _Float16 h2 = (_Float16)hn4.z, h3 = (_Float16)hn4.w;
        f16x4 ph = {h0, h1, h2, h3};
        f16x4 pl = {(_Float16)((hn4.x - (float)h0) * LO_SCALE),
                    (_Float16)((hn4.y - (float)h1) * LO_SCALE),
                    (_Float16)((hn4.z - (float)h2) * LO_SCALE),
                    (_Float16)((hn4.w - (float)h3) * LO_SCALE)};
        *(f16x4*)(Ahi + (size_t)n * DIM + q * 4) = ph;
        *(f16x4*)(Alo + (size_t)n * DIM + q * 4) = pl;
    } else {
        // ---------- slow path: original 64-lane algorithm, run for both nodes ----
        for (int tt = 0; tt < 2; ++tt) {
            int nn = blockIdx.x * 8 + wv * 2 + tt;
            int cnt = cursor[nn];
            if (cnt > CAP) cnt = CAP;
            int v = (lane < cnt) ? bucket[nn * CAP + lane] : 0x7fffffff;
#pragma unroll
            for (int k = 2; k <= 64; k <<= 1) {
#pragma unroll
                for (int j = k >> 1; j >= 1; j >>= 1) {
                    int other = __shfl_xor(v, j);
                    bool lower = ((lane & j) == 0);
                    bool asc = ((lane & k) == 0);
                    int mn = min(v, other), mx = max(v, other);
                    v = (lower == asc) ? mn : mx;
                }
            }
            const float2* x2 = (const float2*)x;
            float ax = 0.f, ay = 0.f;
            for (int j = 0; j < cnt; ++j) {
                int s = __shfl(v, j);
                float2 t = x2[(size_t)s * 64 + lane];
                ax += t.x; ay += t.y;
            }
            float degf = (float)(cnt > 0 ? cnt : 1);
            float hx = ax / degf, hy = ay / degf;
            float ss = hx * hx + hy * hy;
#pragma unroll
            for (int o = 1; o < 64; o <<= 1) ss += __shfl_xor(ss, o);
            float denom = sqrtf(ss) + EPSV;
            float hnx = hx / denom, hny = hy / denom;
            ((float2*)h)[(size_t)nn * 64 + lane] = make_float2(hx, hy);
            _Float16 hix = (_Float16)hnx, hiy = (_Float16)hny;
            f16x2 ph; ph[0] = hix; ph[1] = hiy;
            f16x2 pl; pl[0] = (_Float16)((hnx - (float)hix) * LO_SCALE);
            pl[1] = (_Float16)((hny - (float)hiy) * LO_SCALE);
            *(f16x2*)(Ahi + (size_t)nn * DIM + lane * 2) = ph;
            *(f16x2*)(Alo + (size_t)nn * DIM + lane * 2) = pl;
        }
    }
}

// ---------------- Stage 3: LDS-shared MFMA fp16x3 sim, N-complete (R9 proven) -----
// 4 waves x 32 rows, all 1024 cents per block (32 chunks of 32): NO cross-block
// combine (no part buffer, no decode pass, no keys memset). Writes assign
// directly + fused cluster_count (50K atomics on 1024 hot counters).
#define SWZ14(u) ((u) ^ ((((u) >> 8) & 7) << 4))

__global__ __launch_bounds__(256, 3) void sim_mfma3_k(const _Float16* __restrict__ Ahi,
                                                      const _Float16* __restrict__ Alo,
                                                      int* __restrict__ assign,
                                                      int* __restrict__ counts) {
    __shared__ __align__(16) char Bs[2][16384];  // [dbuf][hi 8192 | lo 8192]
    const int lane = threadIdx.x & 63;
    const int wv = threadIdx.x >> 6;
    const int r16 = lane & 15, kg = lane >> 4;
    const int m0 = blockIdx.x * 128 + wv * 32;

    // ---- A rows -> regs (2 Mtiles x 4 ksub x 2 planes = 64 VGPR), read once ----
    int ar0 = m0 + r16;      if (ar0 > N_NODES - 1) ar0 = N_NODES - 1;
    int ar1 = m0 + 16 + r16; if (ar1 > N_NODES - 1) ar1 = N_NODES - 1;
    f16x8 ah0[4], al0[4], ah1[4], al1[4];
#pragma unroll
    for (int ks = 0; ks < 4; ++ks) {
        size_t o0 = (size_t)ar0 * DIM + ks * 32 + kg * 8;
        size_t o1 = (size_t)ar1 * DIM + ks * 32 + kg * 8;
        ah0[ks] = *(const f16x8*)(Ahi + o0);
        al0[ks] = *(const f16x8*)(Alo + o0);
        ah1[ks] = *(const f16x8*)(Ahi + o1);
        al1[ks] = *(const f16x8*)(Alo + o1);
    }

    // ---- staging constants: per wave 4KB of the 16KB chunk (2KB per plane) ----
    const int u0 = wv * 2048 + lane * 16;   // byte slot in plane (linear)
    const int u1 = u0 + 1024;
    const int d0 = SWZ14(u0), d1 = SWZ14(u1);
    const int e0 = u0 >> 1, e1 = u1 >> 1;   // element offsets

    float best0_0 = -1e30f, best0_1 = -1e30f, best0_2 = -1e30f, best0_3 = -1e30f;
    float best1_0 = -1e30f, best1_1 = -1e30f, best1_2 = -1e30f, best1_3 = -1e30f;
    int bi0_0 = 0, bi0_1 = 0, bi0_2 = 0, bi0_3 = 0;
    int bi1_0 = 0, bi1_1 = 0, bi1_2 = 0, bi1_3 = 0;

    const int rbase = r16 * 256;
    const int x4 = (r16 & 7) << 4;

    // prologue: stage chunk 0
    f16x8 sA = *(const f16x8*)(Ahi + e0);
    f16x8 sB = *(const f16x8*)(Ahi + e1);
    f16x8 sC = *(const f16x8*)(Alo + e0);
    f16x8 sD = *(const f16x8*)(Alo + e1);
    {
        char* bc = &Bs[0][0];
        *(f16x8*)(bc + d0) = sA; *(f16x8*)(bc + d1) = sB;
        *(f16x8*)(bc + 8192 + d0) = sC; *(f16x8*)(bc + 8192 + d1) = sD;
    }
    __syncthreads();

    for (int kc = 0; kc < 32; ++kc) {
        const int cur = kc & 1;
        if (kc < 31) {  // issue next chunk's global loads (fly under compute)
            int go = (kc + 1) * 4096;
            sA = *(const f16x8*)(Ahi + go + e0);
            sB = *(const f16x8*)(Ahi + go + e1);
            sC = *(const f16x8*)(Alo + go + e0);
            sD = *(const f16x8*)(Alo + go + e1);
        }
        char* bc = &Bs[cur][0];
#pragma unroll
        for (int ns = 0; ns < 2; ++ns) {
            f32x4 c1a = (f32x4){0.f, 0.f, 0.f, 0.f};
            f32x4 c2a = (f32x4){0.f, 0.f, 0.f, 0.f};
            f32x4 c1b = (f32x4){0.f, 0.f, 0.f, 0.f};
            f32x4 c2b = (f32x4){0.f, 0.f, 0.f, 0.f};
#pragma unroll
            for (int ks = 0; ks < 4; ++ks) {
                int off = ns * 4096 + rbase + ((ks * 64 + kg * 16) ^ x4);
                f16x8 bh = *(const f16x8*)(bc + off);
                f16x8 bl = *(const f16x8*)(bc + 8192 + off);
                c1a = __builtin_amdgcn_mfma_f32_16x16x32_f16(ah0[ks], bh, c1a, 0, 0, 0);
                c2a = __builtin_amdgcn_mfma_f32_16x16x32_f16(ah0[ks], bl, c2a, 0, 0, 0);
                c2a = __builtin_amdgcn_mfma_f32_16x16x32_f16(al0[ks], bh, c2a, 0, 0, 0);
                c1b = __builtin_amdgcn_mfma_f32_16x16x32_f16(ah1[ks], bh, c1b, 0, 0, 0);
                c2b = __builtin_amdgcn_mfma_f32_16x16x32_f16(ah1[ks], bl, c2b, 0, 0, 0);
                c2b = __builtin_amdgcn_mfma_f32_16x16x32_f16(al1[ks], bh, c2b, 0, 0, 0);
            }
            int col = kc * 32 + ns * 16 + r16;   // ascending per lane
            float s;
            s = c1a[0] + c2a[0] * INV_LO_SCALE; if (s > best0_0) { best0_0 = s; bi0_0 = col; }
            s = c1a[1] + c2a[1] * INV_LO_SCALE; if (s > best0_1) { best0_1 = s; bi0_1 = col; }
            s = c1a[2] + c2a[2] * INV_LO_SCALE; if (s > best0_2) { best0_2 = s; bi0_2 = col; }
            s = c1a[3] + c2a[3] * INV_LO_SCALE; if (s > best0_3) { best0_3 = s; bi0_3 = col; }
            s = c1b[0] + c2b[0] * INV_LO_SCALE; if (s > best1_0) { best1_0 = s; bi1_0 = col; }
            s = c1b[1] + c2b[1] * INV_LO_SCALE; if (s > best1_1) { best1_1 = s; bi1_1 = col; }
            s = c1b[2] + c2b[2] * INV_LO_SCALE; if (s > best1_2) { best1_2 = s; bi1_2 = col; }
            s = c1b[3] + c2b[3] * INV_LO_SCALE; if (s > best1_3) { best1_3 = s; bi1_3 = col; }
        }
        if (kc < 31) {  // write next chunk into the other buffer
            char* bn = &Bs[cur ^ 1][0];
            *(f16x8*)(bn + d0) = sA; *(f16x8*)(bn + d1) = sB;
            *(f16x8*)(bn + 8192 + d0) = sC; *(f16x8*)(bn + 8192 + d1) = sD;
        }
        __syncthreads();
    }

    // ---- finalize: 16-lane reduce (min-index tiebreak = np first-max) ----
    float bestA[8] = {best0_0, best0_1, best0_2, best0_3,
                      best1_0, best1_1, best1_2, best1_3};
    int bidxA[8] = {bi0_0, bi0_1, bi0_2, bi0_3, bi1_0, bi1_1, bi1_2, bi1_3};
#pragma unroll
    for (int qq = 0; qq < 8; ++qq) {
        float b = bestA[qq];
        int bi = bidxA[qq];
#pragma unroll
        for (int o = 1; o < 16; o <<= 1) {
            float os = __shfl_xor(b, o);
            int oi = __shfl_xor(bi, o);
            if (os > b || (os == b && oi < bi)) { b = os; bi = oi; }
        }
        if (r16 == 0) {
            int gr = m0 + (qq >> 2) * 16 + kg * 4 + (qq & 3);  // C/D row = kg*4 + reg
            if (gr < N_NODES) {
                assign[gr] = bi;
                atomicAdd(counts + bi, 1);   // fused cluster_count
            }
        }
    }
}

// ---------------- Stage 4: scan (shfl-based, 3 barriers) + compact ----------------
__global__ void scan_k(const int* __restrict__ counts, int* __restrict__ offs,
                       int* __restrict__ ccur) {
    __shared__ int wsum[4];
    int t = threadIdx.x;              // 256 threads x 4 elements
    int lane = t & 63, wv = t >> 6;
    int4 v = ((const int4*)counts)[t];
    int s = v.x + v.y + v.z + v.w;
    int ps = s;
#pragma unroll
    for (int o = 1; o < 64; o <<= 1) {
        int u = __shfl_up(ps, o);
        if (lane >= o) ps += u;
    }
    if (lane == 63) wsum[wv] = ps;
    __syncthreads();
    int base = 0;
#pragma unroll
    for (int w = 0; w < 4; ++w) base += (w < wv) ? wsum[w] : 0;
    int excl = base + ps - s;
    int4 o4;
    o4.x = excl;
    o4.y = excl + v.x;
    o4.z = excl + v.x + v.y;
    o4.w = excl + v.x + v.y + v.z;
    ((int4*)offs)[t] = o4;
    ((int4*)ccur)[t] = o4;
}

__global__ void fill_clist_k(const int* __restrict__ assign, int* __restrict__ ccur,
                             int* __restrict__ clist) {
    int n = blockIdx.x * 256 + threadIdx.x;
    if (n >= N_NODES) return;
    int p = atomicAdd(ccur + assign[n], 1);
    clist[p] = n;
}

// ---------------- Stage 5 (fused): xc sum + y-row + direct scatter to out --------
__global__ void xcy_out_k(const float* __restrict__ h, const int* __restrict__ clist,
                          const int* __restrict__ offs, const int* __restrict__ counts,
                          const float* __restrict__ W1, const float* __restrict__ b1,
                          float* __restrict__ out) {
    __shared__ float xr[DIM];
    int c = blockIdx.x, t = threadIdx.x;  // 1024 blocks x 128 threads
    int s = offs[c], cnt = counts[c];
    float acc = 0.f;
    for (int i = 0; i < cnt; ++i) {
        int n = clist[s + i];
        acc += h[(size_t)n * DIM + t];
    }
    xr[t] = acc / (float)(cnt > 0 ? cnt : 1);
    __syncthreads();

    const float4* w4 = (const float4*)(W1 + t * DIM);
    float a0 = 0.f, a1 = 0.f, a2 = 0.f, a3 = 0.f;
#pragma unroll
    for (int kk = 0; kk < 32; ++kk) {
        float4 w = w4[kk];
        a0 = fmaf(xr[4 * kk + 0], w.x, a0);
        a1 = fmaf(xr[4 * kk + 1], w.y, a1);
        a2 = fmaf(xr[4 * kk + 2], w.z, a2);
        a3 = fmaf(xr[4 * kk + 3], w.w, a3);
    }
    float yv = (a0 + a1) + (a2 + a3) + b1[t];

    for (int i = 0; i < cnt; ++i) {
        int n = clist[s + i];
        out[(size_t)n * DIM + t] = yv;   // coalesced 512B row write per member
    }
}

extern "C" void kernel_launch(void* const* d_in, const int* in_sizes, int n_in,
                              void* d_out, int out_size, void* d_ws, size_t ws_size,
                              hipStream_t stream) {
    const float* x  = (const float*)d_in[0];
    const int*   ei = (const int*)d_in[1];
    const float* W1 = (const float*)d_in[2];
    const float* b1 = (const float*)d_in[3];
    float* out = (float*)d_out;

    char* ws = (char*)d_ws;
    // ws layout (bytes):
    //   h      @ 0          : 50000*128*4 = 25,600,000
    //   bucket @ 25,600,000 : 50000*64*4  = 12,800,000  (dead after agg_norm:
    //       clist @ 25,600,000 : 200,000 | offs @ 25,800,000 : 4,096
    //       ccur  @ 25,804,096 : 4,096 )
    //   cursor @ 38,400,000 : 50000*4     =    200,000
    //   counts @ 38,600,000 : 1024*4      =      4,096
    //   assign @ 39,128,384 : 50000*4     =    200,000
    float* h      = (float*)(ws);
    int*   bucket = (int*)(ws + 25600000);
    int*   clist  = (int*)(ws + 25600000);
    int*   offs   = (int*)(ws + 25800000);
    int*   ccur   = (int*)(ws + 25804096);
    int*   cursor = (int*)(ws + 38400000);
    int*   counts = (int*)(ws + 38600000);
    int*   assign = (int*)(ws + 39128384);

    // d_out (25.6 MB) temporarily holds the split fp16 planes of hn:
    //   Ahi @ 0 (12.8 MB), Alo @ 12.8 MB. Dead after sim; fully overwritten
    //   by xcy_out_k (every node belongs to exactly one cluster).
    _Float16* Ahi = (_Float16*)d_out;
    _Float16* Alo = (_Float16*)((char*)d_out + 12800000);

    hipMemsetAsync(ws + 38400000, 0, 204096, stream);  // cursor + counts

    fill_buckets_k<<<(N_EDGES + 255) / 256, 256, 0, stream>>>(ei, bucket, cursor);
    agg_norm_k<<<N_NODES / 8, 256, 0, stream>>>(x, bucket, cursor, h, Ahi, Alo);
    sim_mfma3_k<<<(N_NODES + 127) / 128, 256, 0, stream>>>(Ahi, Alo, assign, counts);
    scan_k<<<1, 256, 0, stream>>>(counts, offs, ccur);
    fill_clist_k<<<(N_NODES + 255) / 256, 256, 0, stream>>>(assign, ccur, clist);
    xcy_out_k<<<KC, 128, 0, stream>>>(h, clist, offs, counts, W1, b1, out);
}